// Round 1
// baseline (453.958 us; speedup 1.0000x reference)
//
#include <hip/hip_runtime.h>
#include <hip/hip_bf16.h>

#define NN 8192
#define FIN 256
#define FO 128
#define KSPLIT 8
#define JCHUNK 1024             // cols per wave
#define NSTEP 16                // 64-col steps
#define GSTRIDE 260             // floats per 4-row LDS group (1024 B + 16 B pad)
#define L2E 1.4426950408889634f
#define C2  0.28853900817779268f   // 0.2 * log2(e)

typedef __bf16 bf16x8 __attribute__((ext_vector_type(8)));
typedef __bf16 bf16x2 __attribute__((ext_vector_type(2)));
typedef float  f32x4  __attribute__((ext_vector_type(4)));

__device__ __forceinline__ void dma16(const float* g, float* l) {
  __builtin_amdgcn_global_load_lds(
      (__attribute__((address_space(1))) void*)g,
      (__attribute__((address_space(3))) void*)l, 16, 0, 0);
}

// ---------------------------------------------------------------------------
// Kernel 1: h = x@W (fp32 accum), write Bpack (bf16 MFMA-B-fragment layout),
//           f_src = h@a_src, f_dst = h@a_dst (fp32).
// Bpack element (kg, nt, lane=q*16+m, t) = h[j = kg*32+q*8+t][n = nt*16+m]
// ---------------------------------------------------------------------------
__global__ __launch_bounds__(256) void k_proj(
    const float* __restrict__ x, const float* __restrict__ W,
    const float* __restrict__ a_src, const float* __restrict__ a_dst,
    __bf16* __restrict__ Bp, float* __restrict__ f_src, float* __restrict__ f_dst)
{
  __shared__ float xs[16 * FIN];     // 16 KB x-tile
  __shared__ float fs[16], fd[16];
  const int tid = threadIdx.x;
  const int i0 = blockIdx.x * 16;

  const float4* xg = (const float4*)(x + (size_t)i0 * FIN);
  float4* xs4 = (float4*)xs;
  #pragma unroll
  for (int t = 0; t < 4; t++) xs4[tid + 256 * t] = xg[tid + 256 * t];
  if (tid < 16) { fs[tid] = 0.f; fd[tid] = 0.f; }
  __syncthreads();

  const int cq = tid & 31;    // column quad: cols c0..c0+3
  const int rg = tid >> 5;    // row group: rows r0, r0+1
  const int c0 = cq * 4;
  const int r0 = rg * 2;
  float acc0[4] = {0.f,0.f,0.f,0.f};
  float acc1[4] = {0.f,0.f,0.f,0.f};
  const float* xr0 = xs + r0 * FIN;
  const float* xr1 = xs + (r0 + 1) * FIN;

  for (int k = 0; k < FIN; k += 4) {
    float4 xa = *(const float4*)(xr0 + k);
    float4 xb = *(const float4*)(xr1 + k);
    #pragma unroll
    for (int kk = 0; kk < 4; kk++) {
      float4 wv = *(const float4*)(W + (size_t)(k + kk) * FO + c0);
      float xav = ((const float*)&xa)[kk];
      float xbv = ((const float*)&xb)[kk];
      acc0[0] += xav * wv.x; acc0[1] += xav * wv.y;
      acc0[2] += xav * wv.z; acc0[3] += xav * wv.w;
      acc1[0] += xbv * wv.x; acc1[1] += xbv * wv.y;
      acc1[2] += xbv * wv.z; acc1[3] += xbv * wv.w;
    }
  }

  float4 as = *(const float4*)(a_src + c0);
  float4 ad = *(const float4*)(a_dst + c0);
  float ps0 = acc0[0]*as.x + acc0[1]*as.y + acc0[2]*as.z + acc0[3]*as.w;
  float ps1 = acc1[0]*as.x + acc1[1]*as.y + acc1[2]*as.z + acc1[3]*as.w;
  float pd0 = acc0[0]*ad.x + acc0[1]*ad.y + acc0[2]*ad.z + acc0[3]*ad.w;
  float pd1 = acc1[0]*ad.x + acc1[1]*ad.y + acc1[2]*ad.z + acc1[3]*ad.w;
  atomicAdd(&fs[r0],     ps0);
  atomicAdd(&fs[r0 + 1], ps1);
  atomicAdd(&fd[r0],     pd0);
  atomicAdd(&fd[r0 + 1], pd1);

  const int j0 = i0 + r0;
  const int kg = j0 >> 5;
  const int q  = (j0 >> 3) & 3;
  const int t0 = j0 & 7;
  #pragma unroll
  for (int c = 0; c < 4; c++) {
    const int n = c0 + c;
    bf16x2 v;
    v[0] = (__bf16)acc0[c];
    v[1] = (__bf16)acc1[c];
    size_t idx = ((size_t)(kg * 8 + (n >> 4)) * 64 + q * 16 + (n & 15)) * 8 + t0;
    *(bf16x2*)(Bp + idx) = v;
  }
  __syncthreads();
  if (tid < 16) { f_src[i0 + tid] = fs[tid]; f_dst[i0 + tid] = fd[tid]; }
}

// ---------------------------------------------------------------------------
// Kernel 2: DMA-staged streaming P@H — barrier-free pipelined version.
// 512 blocks x 256 thr (4 waves). Wave owns 32 rows x 1024 cols; two 16-row
// m-tiles share each B-frag. atile is strictly PER-WAVE ([w][buf]) and G1/G2
// are read-only after init, so the main loop needs NO __syncthreads (the old
// per-step barrier's vmcnt(0) drain serialized every step against HBM
// latency). New schedule per step:
//   top:  asm s_waitcnt vmcnt(0)   <- waits only the prefetch issued last iter
//   consume buf (LDS reads, p-compute, Bp loads, MFMA)
//   end:  ISSUE(next)              <- youngest vmem ops; compiler's Bp waits
//                                     can never force-drain them
// Each 8-DMA batch gets a full consume phase (~700-900 cy) to land -> HBM
// latency hidden; waves pipeline independently (no barrier convoy).
// vmcnt(0) (not counted N) is immune to spill/extra-vmem counting hazards.
// ---------------------------------------------------------------------------
__global__ __launch_bounds__(256, 2) void k_attn(
    const float* __restrict__ adj, const __bf16* __restrict__ Bp,
    const float* __restrict__ f_src, const float* __restrict__ f_dst,
    float* __restrict__ num, float* __restrict__ lsum)
{
  __shared__ float G1[JCHUNK];                         // 4 KB
  __shared__ float G2[JCHUNK];                         // 4 KB
  __shared__ __align__(16) float atile[4][2][8 * GSTRIDE];  // 65 KB

  const int tid = threadIdx.x;
  const int rb = blockIdx.x >> 3;     // 0..63 (128 rows per block)
  const int ks = blockIdx.x & 7;
  const int i0 = rb * 128;
  const int jbase = ks * JCHUNK;

  const int w = tid >> 6;
  const int lane = tid & 63;
  const int m = lane & 15;
  const int q = lane >> 4;
  const int wbase = i0 + w * 32;

  float F1[2], F2[2];
  #pragma unroll
  for (int mt = 0; mt < 2; mt++) {
    float s = f_src[wbase + mt * 16 + m];
    F1[mt] = __builtin_amdgcn_exp2f(s * L2E);
    F2[mt] = __builtin_amdgcn_exp2f(s * C2);
  }

  #pragma unroll
  for (int t = 0; t < 4; t++) {
    int j = tid + t * 256;
    float d = f_dst[jbase + j];
    G1[j] = __builtin_amdgcn_exp2f(d * L2E);
    G2[j] = __builtin_amdgcn_exp2f(d * C2);
  }
  __syncthreads();   // G1/G2 visible to all waves; only barrier in the kernel

  f32x4 acc[2][8];
  #pragma unroll
  for (int mt = 0; mt < 2; mt++)
    #pragma unroll
    for (int nt = 0; nt < 8; nt++) acc[mt][nt] = (f32x4){0.f, 0.f, 0.f, 0.f};
  float psum[2] = {0.f, 0.f};

  // DMA source: lane covers row (lane>>4) of each 4-row group, 16B at (lane&15)*16
  const float* gsrc = adj + (size_t)(wbase + (lane >> 4)) * NN + jbase + (lane & 15) * 4;
  float* tw0 = &atile[w][0][0];
  float* tw1 = &atile[w][1][0];

#define ISSUE(buf, step)                                                      \
  {                                                                           \
    const float* gs = gsrc + (step) * 64;                                     \
    float* lb = (buf) ? tw1 : tw0;                                            \
    _Pragma("unroll")                                                         \
    for (int g = 0; g < 8; g++)                                               \
      dma16(gs + (size_t)g * 4 * NN, lb + g * GSTRIDE);                       \
  }

  ISSUE(0, 0)

  for (int step = 0; step < NSTEP; ++step) {
    const int buf = step & 1;
    // Wait for this step's prefetch (issued at end of previous iteration).
    // Memory clobber: no LDS read of atile may hoist above this wait.
    asm volatile("s_waitcnt vmcnt(0)" ::: "memory");

    const float* tb = buf ? tw1 : tw0;
    #pragma unroll
    for (int kg = 0; kg < 2; kg++) {
      const int jj = step * 64 + kg * 32 + q * 8;
      float4 u0 = *(const float4*)(G1 + jj);
      float4 u1 = *(const float4*)(G1 + jj + 4);
      float4 v0 = *(const float4*)(G2 + jj);
      float4 v1 = *(const float4*)(G2 + jj + 4);

      bf16x8 af[2];
      #pragma unroll
      for (int mt = 0; mt < 2; mt++) {
        const int r = mt * 16 + m;
        const float* ap = tb + (r >> 2) * GSTRIDE + (r & 3) * 64 + kg * 32 + q * 8;
        float4 a0 = *(const float4*)ap;
        float4 a1 = *(const float4*)(ap + 4);
        const float f1 = F1[mt], f2 = F2[mt];
        float p0 = (a0.x > 0.f) ? fmaxf(f1 * u0.x, f2 * v0.x) : 0.f;
        float p1 = (a0.y > 0.f) ? fmaxf(f1 * u0.y, f2 * v0.y) : 0.f;
        float p2 = (a0.z > 0.f) ? fmaxf(f1 * u0.z, f2 * v0.z) : 0.f;
        float p3 = (a0.w > 0.f) ? fmaxf(f1 * u0.w, f2 * v0.w) : 0.f;
        float p4 = (a1.x > 0.f) ? fmaxf(f1 * u1.x, f2 * v1.x) : 0.f;
        float p5 = (a1.y > 0.f) ? fmaxf(f1 * u1.y, f2 * v1.y) : 0.f;
        float p6 = (a1.z > 0.f) ? fmaxf(f1 * u1.z, f2 * v1.z) : 0.f;
        float p7 = (a1.w > 0.f) ? fmaxf(f1 * u1.w, f2 * v1.w) : 0.f;
        psum[mt] += ((p0 + p1) + (p2 + p3)) + ((p4 + p5) + (p6 + p7));
        bf16x8 a;
        a[0] = (__bf16)p0; a[1] = (__bf16)p1; a[2] = (__bf16)p2; a[3] = (__bf16)p3;
        a[4] = (__bf16)p4; a[5] = (__bf16)p5; a[6] = (__bf16)p6; a[7] = (__bf16)p7;
        af[mt] = a;
      }

      const __bf16* bsrc = Bp + (size_t)(ks * 32 + step * 2 + kg) * 4096 + lane * 8;
      #pragma unroll
      for (int nt = 0; nt < 8; nt++) {
        bf16x8 bfrag = *(const bf16x8*)(bsrc + nt * 512);
        acc[0][nt] = __builtin_amdgcn_mfma_f32_16x16x32_bf16(af[0], bfrag, acc[0][nt], 0, 0, 0);
        acc[1][nt] = __builtin_amdgcn_mfma_f32_16x16x32_bf16(af[1], bfrag, acc[1][nt], 0, 0, 0);
      }
    }

    // Prefetch next step into the other buffer — issued LAST so these are
    // the youngest vmem ops (no compiler wait can target anything younger).
    if (step + 1 < NSTEP) ISSUE(buf ^ 1, step + 1)
  }
#undef ISSUE

  // denominators: rows keyed by m live in lanes {m, m+16, m+32, m+48}
  #pragma unroll
  for (int mt = 0; mt < 2; mt++) {
    float p = psum[mt];
    p += __shfl_xor(p, 16);
    p += __shfl_xor(p, 32);
    if (lane < 16) atomicAdd(&lsum[wbase + mt * 16 + lane], p);
  }

  // numerators: C/D layout row=q*4+r, col=nt*16+m
  #pragma unroll
  for (int mt = 0; mt < 2; mt++) {
    const int rb0 = wbase + mt * 16 + q * 4;
    #pragma unroll
    for (int nt = 0; nt < 8; nt++) {
      #pragma unroll
      for (int r = 0; r < 4; r++) {
        atomicAdd(&num[(size_t)(rb0 + r) * FO + nt * 16 + m], acc[mt][nt][r]);
      }
    }
  }
}

// ---------------------------------------------------------------------------
// Kernel 3: out = num / l, vectorized float4.
// ---------------------------------------------------------------------------
__global__ __launch_bounds__(256) void k_div(
    const float* __restrict__ num, const float* __restrict__ lsum,
    float* __restrict__ out)
{
  int idx = blockIdx.x * 256 + threadIdx.x;        // float4 index
  float4 v = ((const float4*)num)[idx];
  float inv = 1.0f / lsum[idx >> 5];               // 32 float4 per row
  float4 o;
  o.x = v.x * inv; o.y = v.y * inv; o.z = v.z * inv; o.w = v.w * inv;
  ((float4*)out)[idx] = o;
}

extern "C" void kernel_launch(void* const* d_in, const int* in_sizes, int n_in,
                              void* d_out, int out_size, void* d_ws, size_t ws_size,
                              hipStream_t stream) {
  const float* x     = (const float*)d_in[0];
  const float* adj   = (const float*)d_in[1];
  const float* W     = (const float*)d_in[2];
  const float* a_src = (const float*)d_in[3];
  const float* a_dst = (const float*)d_in[4];
  float* out = (float*)d_out;

  char* ws = (char*)d_ws;
  __bf16* Bp   = (__bf16*)ws;                                  // 2 MB
  float* f_src = (float*)(ws + 2097152);                       // 32 KB
  float* f_dst = (float*)(ws + 2097152 + 32768);               // 32 KB
  float* num   = (float*)(ws + 2097152 + 65536);               // 4 MB
  float* lsum  = (float*)(ws + 2097152 + 65536 + 4194304);     // 32 KB

  hipMemsetAsync(num, 0, 4194304 + 32768, stream);             // zero num + lsum
  hipLaunchKernelGGL(k_proj, dim3(512), dim3(256), 0, stream,
                     x, W, a_src, a_dst, Bp, f_src, f_dst);
  hipLaunchKernelGGL(k_attn, dim3(512), dim3(256), 0, stream,
                     adj, Bp, f_src, f_dst, num, lsum);
  hipLaunchKernelGGL(k_div, dim3(1024), dim3(256), 0, stream,
                     num, lsum, out);
}

// Round 2
// 442.026 us; speedup vs baseline: 1.0270x; 1.0270x over previous
//
#include <hip/hip_runtime.h>
#include <hip/hip_bf16.h>

#define NN 8192
#define FIN 256
#define FO 128
#define KSPLIT 8
#define JCHUNK 1024             // cols per wave
#define NSTEP 16                // 64-col steps
#define L2E 1.4426950408889634f
#define C2  0.28853900817779268f   // 0.2 * log2(e)

typedef __bf16 bf16x8 __attribute__((ext_vector_type(8)));
typedef __bf16 bf16x2 __attribute__((ext_vector_type(2)));
typedef float  f32x4  __attribute__((ext_vector_type(4)));

// ---------------------------------------------------------------------------
// Kernel 1: h = x@W (fp32 accum), write Bpack (bf16 MFMA-B-fragment layout),
//           f_src = h@a_src, f_dst = h@a_dst (fp32).
// Bpack element (kg, nt, lane=q*16+m, t) = h[j = kg*32+q*8+t][n = nt*16+m]
// ---------------------------------------------------------------------------
__global__ __launch_bounds__(256) void k_proj(
    const float* __restrict__ x, const float* __restrict__ W,
    const float* __restrict__ a_src, const float* __restrict__ a_dst,
    __bf16* __restrict__ Bp, float* __restrict__ f_src, float* __restrict__ f_dst)
{
  __shared__ float xs[16 * FIN];     // 16 KB x-tile
  __shared__ float fs[16], fd[16];
  const int tid = threadIdx.x;
  const int i0 = blockIdx.x * 16;

  const float4* xg = (const float4*)(x + (size_t)i0 * FIN);
  float4* xs4 = (float4*)xs;
  #pragma unroll
  for (int t = 0; t < 4; t++) xs4[tid + 256 * t] = xg[tid + 256 * t];
  if (tid < 16) { fs[tid] = 0.f; fd[tid] = 0.f; }
  __syncthreads();

  const int cq = tid & 31;    // column quad: cols c0..c0+3
  const int rg = tid >> 5;    // row group: rows r0, r0+1
  const int c0 = cq * 4;
  const int r0 = rg * 2;
  float acc0[4] = {0.f,0.f,0.f,0.f};
  float acc1[4] = {0.f,0.f,0.f,0.f};
  const float* xr0 = xs + r0 * FIN;
  const float* xr1 = xs + (r0 + 1) * FIN;

  for (int k = 0; k < FIN; k += 4) {
    float4 xa = *(const float4*)(xr0 + k);
    float4 xb = *(const float4*)(xr1 + k);
    #pragma unroll
    for (int kk = 0; kk < 4; kk++) {
      float4 wv = *(const float4*)(W + (size_t)(k + kk) * FO + c0);
      float xav = ((const float*)&xa)[kk];
      float xbv = ((const float*)&xb)[kk];
      acc0[0] += xav * wv.x; acc0[1] += xav * wv.y;
      acc0[2] += xav * wv.z; acc0[3] += xav * wv.w;
      acc1[0] += xbv * wv.x; acc1[1] += xbv * wv.y;
      acc1[2] += xbv * wv.z; acc1[3] += xbv * wv.w;
    }
  }

  float4 as = *(const float4*)(a_src + c0);
  float4 ad = *(const float4*)(a_dst + c0);
  float ps0 = acc0[0]*as.x + acc0[1]*as.y + acc0[2]*as.z + acc0[3]*as.w;
  float ps1 = acc1[0]*as.x + acc1[1]*as.y + acc1[2]*as.z + acc1[3]*as.w;
  float pd0 = acc0[0]*ad.x + acc0[1]*ad.y + acc0[2]*ad.z + acc0[3]*ad.w;
  float pd1 = acc1[0]*ad.x + acc1[1]*ad.y + acc1[2]*ad.z + acc1[3]*ad.w;
  atomicAdd(&fs[r0],     ps0);
  atomicAdd(&fs[r0 + 1], ps1);
  atomicAdd(&fd[r0],     pd0);
  atomicAdd(&fd[r0 + 1], pd1);

  const int j0 = i0 + r0;
  const int kg = j0 >> 5;
  const int q  = (j0 >> 3) & 3;
  const int t0 = j0 & 7;
  #pragma unroll
  for (int c = 0; c < 4; c++) {
    const int n = c0 + c;
    bf16x2 v;
    v[0] = (__bf16)acc0[c];
    v[1] = (__bf16)acc1[c];
    size_t idx = ((size_t)(kg * 8 + (n >> 4)) * 64 + q * 16 + (n & 15)) * 8 + t0;
    *(bf16x2*)(Bp + idx) = v;
  }
  __syncthreads();
  if (tid < 16) { f_src[i0 + tid] = fs[tid]; f_dst[i0 + tid] = fd[tid]; }
}

// ---------------------------------------------------------------------------
// Kernel 2: direct-to-VGPR streaming P@H (no LDS staging of adj).
// Rationale (round-1 counters): DMA+LDS version ran lockstep
// issue-8/wait-all/consume rounds -> 1 TB/s HBM (12% peak), plus 9.8M LDS
// bank-conflict cycles (8-way on atile b128 reads). adj rows are read
// 128B-contiguous per row by lanes (m, q=0..3), so direct global float4
// loads coalesce fine, need no LDS, no bank conflicts, no vmcnt
// choreography. Register double-buffer (bufA/bufB, 1 step ahead, constant
// indices only) gives each step's loads a full compute phase to land;
// per-wave scoreboard + 8 waves/CU keep requests streaming continuously.
// Separable softmax: p = adj ? max(F1_i*G1_j, F2_i*G2_j) : 0.
// ---------------------------------------------------------------------------
__global__ __launch_bounds__(256, 2) void k_attn(
    const float* __restrict__ adj, const __bf16* __restrict__ Bp,
    const float* __restrict__ f_src, const float* __restrict__ f_dst,
    float* __restrict__ num, float* __restrict__ lsum)
{
  __shared__ float G1[JCHUNK];                         // 4 KB
  __shared__ float G2[JCHUNK];                         // 4 KB

  const int tid = threadIdx.x;
  const int rb = blockIdx.x >> 3;     // 0..63 (128 rows per block)
  const int ks = blockIdx.x & 7;
  const int i0 = rb * 128;
  const int jbase = ks * JCHUNK;

  const int w = tid >> 6;
  const int lane = tid & 63;
  const int m = lane & 15;
  const int q = lane >> 4;
  const int wbase = i0 + w * 32;

  float F1[2], F2[2];
  #pragma unroll
  for (int mt = 0; mt < 2; mt++) {
    float s = f_src[wbase + mt * 16 + m];
    F1[mt] = __builtin_amdgcn_exp2f(s * L2E);
    F2[mt] = __builtin_amdgcn_exp2f(s * C2);
  }

  #pragma unroll
  for (int t = 0; t < 4; t++) {
    int j = tid + t * 256;
    float d = f_dst[jbase + j];
    G1[j] = __builtin_amdgcn_exp2f(d * L2E);
    G2[j] = __builtin_amdgcn_exp2f(d * C2);
  }
  __syncthreads();   // G1/G2 visible; only barrier in the kernel

  f32x4 acc[2][8];
  #pragma unroll
  for (int mt = 0; mt < 2; mt++)
    #pragma unroll
    for (int nt = 0; nt < 8; nt++) acc[mt][nt] = (f32x4){0.f, 0.f, 0.f, 0.f};
  float psum[2] = {0.f, 0.f};

  // Per-lane adj row pointers: lane (m,q) reads rows wbase+m / wbase+16+m,
  // 32B at col q*8 within each 32-col kg group. Lanes q=0..3 of one row
  // cover a contiguous 128B segment -> well-coalesced.
  const float* arow0 = adj + (size_t)(wbase + m) * NN + jbase + q * 8;
  const float* arow1 = arow0 + (size_t)16 * NN;
  const __bf16* bsrc_base = Bp + (size_t)ks * 32 * 4096 + lane * 8;

  // buf layout: [mt*4 + kg*2 + half], half 0 = cols q*8..+3, 1 = q*8+4..+7
#define LOADSTEP(dst, s)                                                      \
  {                                                                           \
    const float* _p0 = arow0 + (s) * 64;                                      \
    const float* _p1 = arow1 + (s) * 64;                                      \
    dst[0] = *(const float4*)(_p0);                                           \
    dst[1] = *(const float4*)(_p0 + 4);                                       \
    dst[2] = *(const float4*)(_p0 + 32);                                      \
    dst[3] = *(const float4*)(_p0 + 36);                                      \
    dst[4] = *(const float4*)(_p1);                                           \
    dst[5] = *(const float4*)(_p1 + 4);                                       \
    dst[6] = *(const float4*)(_p1 + 32);                                      \
    dst[7] = *(const float4*)(_p1 + 36);                                      \
  }

#define COMPUTE(buf, step)                                                    \
  {                                                                           \
    _Pragma("unroll")                                                         \
    for (int kg = 0; kg < 2; kg++) {                                          \
      const int jj = (step) * 64 + kg * 32 + q * 8;                           \
      float4 u0 = *(const float4*)(G1 + jj);                                  \
      float4 u1 = *(const float4*)(G1 + jj + 4);                              \
      float4 v0 = *(const float4*)(G2 + jj);                                  \
      float4 v1 = *(const float4*)(G2 + jj + 4);                              \
      bf16x8 af[2];                                                           \
      _Pragma("unroll")                                                       \
      for (int mt = 0; mt < 2; mt++) {                                        \
        float4 a0 = buf[mt * 4 + kg * 2 + 0];                                 \
        float4 a1 = buf[mt * 4 + kg * 2 + 1];                                 \
        const float f1 = F1[mt], f2 = F2[mt];                                 \
        float p0 = (a0.x > 0.f) ? fmaxf(f1 * u0.x, f2 * v0.x) : 0.f;          \
        float p1 = (a0.y > 0.f) ? fmaxf(f1 * u0.y, f2 * v0.y) : 0.f;          \
        float p2 = (a0.z > 0.f) ? fmaxf(f1 * u0.z, f2 * v0.z) : 0.f;          \
        float p3 = (a0.w > 0.f) ? fmaxf(f1 * u0.w, f2 * v0.w) : 0.f;          \
        float p4 = (a1.x > 0.f) ? fmaxf(f1 * u1.x, f2 * v1.x) : 0.f;          \
        float p5 = (a1.y > 0.f) ? fmaxf(f1 * u1.y, f2 * v1.y) : 0.f;          \
        float p6 = (a1.z > 0.f) ? fmaxf(f1 * u1.z, f2 * v1.z) : 0.f;          \
        float p7 = (a1.w > 0.f) ? fmaxf(f1 * u1.w, f2 * v1.w) : 0.f;          \
        psum[mt] += ((p0 + p1) + (p2 + p3)) + ((p4 + p5) + (p6 + p7));        \
        bf16x8 a;                                                             \
        a[0] = (__bf16)p0; a[1] = (__bf16)p1; a[2] = (__bf16)p2;              \
        a[3] = (__bf16)p3; a[4] = (__bf16)p4; a[5] = (__bf16)p5;              \
        a[6] = (__bf16)p6; a[7] = (__bf16)p7;                                 \
        af[mt] = a;                                                           \
      }                                                                       \
      const __bf16* bsrc = bsrc_base + (size_t)((step) * 2 + kg) * 4096;      \
      _Pragma("unroll")                                                       \
      for (int nt = 0; nt < 8; nt++) {                                        \
        bf16x8 bfrag = *(const bf16x8*)(bsrc + nt * 512);                     \
        acc[0][nt] = __builtin_amdgcn_mfma_f32_16x16x32_bf16(af[0], bfrag, acc[0][nt], 0, 0, 0); \
        acc[1][nt] = __builtin_amdgcn_mfma_f32_16x16x32_bf16(af[1], bfrag, acc[1][nt], 0, 0, 0); \
      }                                                                       \
    }                                                                         \
  }

  float4 bufA[8], bufB[8];
  LOADSTEP(bufA, 0)
  for (int step = 0; step < NSTEP; step += 2) {
    LOADSTEP(bufB, step + 1)
    COMPUTE(bufA, step)
    if (step + 2 < NSTEP) LOADSTEP(bufA, step + 2)
    COMPUTE(bufB, step + 1)
  }
#undef LOADSTEP
#undef COMPUTE

  // denominators: rows keyed by m live in lanes {m, m+16, m+32, m+48}
  #pragma unroll
  for (int mt = 0; mt < 2; mt++) {
    float p = psum[mt];
    p += __shfl_xor(p, 16);
    p += __shfl_xor(p, 32);
    if (lane < 16) atomicAdd(&lsum[wbase + mt * 16 + lane], p);
  }

  // numerators: C/D layout row=q*4+r, col=nt*16+m
  #pragma unroll
  for (int mt = 0; mt < 2; mt++) {
    const int rb0 = wbase + mt * 16 + q * 4;
    #pragma unroll
    for (int nt = 0; nt < 8; nt++) {
      #pragma unroll
      for (int r = 0; r < 4; r++) {
        atomicAdd(&num[(size_t)(rb0 + r) * FO + nt * 16 + m], acc[mt][nt][r]);
      }
    }
  }
}

// ---------------------------------------------------------------------------
// Kernel 3: out = num / l, vectorized float4.
// ---------------------------------------------------------------------------
__global__ __launch_bounds__(256) void k_div(
    const float* __restrict__ num, const float* __restrict__ lsum,
    float* __restrict__ out)
{
  int idx = blockIdx.x * 256 + threadIdx.x;        // float4 index
  float4 v = ((const float4*)num)[idx];
  float inv = 1.0f / lsum[idx >> 5];               // 32 float4 per row
  float4 o;
  o.x = v.x * inv; o.y = v.y * inv; o.z = v.z * inv; o.w = v.w * inv;
  ((float4*)out)[idx] = o;
}

extern "C" void kernel_launch(void* const* d_in, const int* in_sizes, int n_in,
                              void* d_out, int out_size, void* d_ws, size_t ws_size,
                              hipStream_t stream) {
  const float* x     = (const float*)d_in[0];
  const float* adj   = (const float*)d_in[1];
  const float* W     = (const float*)d_in[2];
  const float* a_src = (const float*)d_in[3];
  const float* a_dst = (const float*)d_in[4];
  float* out = (float*)d_out;

  char* ws = (char*)d_ws;
  __bf16* Bp   = (__bf16*)ws;                                  // 2 MB
  float* f_src = (float*)(ws + 2097152);                       // 32 KB
  float* f_dst = (float*)(ws + 2097152 + 32768);               // 32 KB
  float* num   = (float*)(ws + 2097152 + 65536);               // 4 MB
  float* lsum  = (float*)(ws + 2097152 + 65536 + 4194304);     // 32 KB

  hipMemsetAsync(num, 0, 4194304 + 32768, stream);             // zero num + lsum
  hipLaunchKernelGGL(k_proj, dim3(512), dim3(256), 0, stream,
                     x, W, a_src, a_dst, Bp, f_src, f_dst);
  hipLaunchKernelGGL(k_attn, dim3(512), dim3(256), 0, stream,
                     adj, Bp, f_src, f_dst, num, lsum);
  hipLaunchKernelGGL(k_div, dim3(1024), dim3(256), 0, stream,
                     num, lsum, out);
}